// Round 11
// baseline (55.178 us; speedup 1.0000x reference)
//
#include <hip/hip_runtime.h>
#include <math.h>

// Problem constants
#define BB   32
#define CC   256
#define HH   56
#define WW   56
#define HID  512
#define RNK  8
#define HWN  (HH * WW)     // 3136
#define HW4  (HWN / 4)     // 784 float4 per (b,c) plane

// Native clang vector for nontemporal builtins (HIP_vector_type is rejected).
typedef float vf4 __attribute__((ext_vector_type(4)));

__device__ __forceinline__ float gelu_exact(float v) {
    return 0.5f * v * (1.0f + erff(v * 0.70710678118654752f));
}
__device__ __forceinline__ float dot4(float4 a, float4 b) {
    return a.x * b.x + a.y * b.y + a.z * b.z + a.w * b.w;
}

// ---------------------------------------------------------------------------
// Kernel 1: global average pool.  One 256-thread block per (b,c) plane.
// Non-temporal loads: x is read exactly once per replay.
// ---------------------------------------------------------------------------
__global__ __launch_bounds__(256) void pool_kernel(const float* __restrict__ x,
                                                   float* __restrict__ y) {
    const int bc  = blockIdx.x;
    const int tid = threadIdx.x;
    const vf4* xp = reinterpret_cast<const vf4*>(x) + (size_t)bc * HW4;

    float s = 0.0f;
    for (int p = tid; p < HW4; p += 256) {
        vf4 v = __builtin_nontemporal_load(xp + p);
        s += (v.x + v.y) + (v.z + v.w);
    }
    #pragma unroll
    for (int off = 32; off > 0; off >>= 1) s += __shfl_down(s, off, 64);

    __shared__ float ls[4];
    const int wave = tid >> 6;
    if ((tid & 63) == 0) ls[wave] = s;
    __syncthreads();
    if (tid == 0) {
        float t = (ls[0] + ls[1]) + (ls[2] + ls[3]);
        y[bc] = t * (1.0f / (float)HWN);
    }
}

// ---------------------------------------------------------------------------
// Kernel 2: stages 1-3, GPU-wide via redundant slicing (unchanged, round 9).
// 256 blocks = 8 slices per batch; h/yp computed redundantly per block in
// LDS (weights L2-resident), ab rows written exactly once.
// ---------------------------------------------------------------------------
__global__ __launch_bounds__(1024) void middle_kernel(
        const float* __restrict__ y,  const float* __restrict__ w1,
        const float* __restrict__ w2, const float* __restrict__ wA,
        const float* __restrict__ wB, float* __restrict__ ab) {
    const int b     = blockIdx.x >> 3;    // batch 0..31
    const int slice = blockIdx.x & 7;     // 0..7
    const int tid   = threadIdx.x;        // 0..1023

    __shared__ float y_s[CC];
    __shared__ float h_s[HID];
    __shared__ float yp_s[CC];

    if (tid < CC) y_s[tid] = y[b * CC + tid];
    __syncthreads();

    // Stage 1: h[j] = gelu(dot(y, w1[j])), 512 rows, K=256.
    {
        const int sub = tid & 7;
        const int rg  = tid >> 3;         // 0..127
        const float4* ys4 = reinterpret_cast<const float4*>(y_s);
        float4 yv[8];
        #pragma unroll
        for (int k = 0; k < 8; ++k) yv[k] = ys4[sub + 8 * k];
        #pragma unroll
        for (int pass = 0; pass < 4; ++pass) {
            const int row = pass * 128 + rg;
            const float4* wr = reinterpret_cast<const float4*>(w1 + (size_t)row * CC);
            float d = 0.0f;
            #pragma unroll
            for (int k = 0; k < 8; ++k) d += dot4(wr[sub + 8 * k], yv[k]);
            d += __shfl_xor(d, 1, 64);
            d += __shfl_xor(d, 2, 64);
            d += __shfl_xor(d, 4, 64);
            if (sub == 0) h_s[row] = gelu_exact(d);
        }
    }
    __syncthreads();

    // Stage 2: yp[i] = gelu(dot(h, w2[i])), 256 rows, K=512.
    {
        const int sub = tid & 15;
        const int rg  = tid >> 4;         // 0..63
        const float4* hs4 = reinterpret_cast<const float4*>(h_s);
        float4 hv[8];
        #pragma unroll
        for (int k = 0; k < 8; ++k) hv[k] = hs4[sub + 16 * k];
        #pragma unroll
        for (int pass = 0; pass < 4; ++pass) {
            const int row = pass * 64 + rg;
            const float4* wr = reinterpret_cast<const float4*>(w2 + (size_t)row * HID);
            float d = 0.0f;
            #pragma unroll
            for (int k = 0; k < 8; ++k) d += dot4(wr[sub + 16 * k], hv[k]);
            d += __shfl_xor(d, 1, 64);
            d += __shfl_xor(d, 2, 64);
            d += __shfl_xor(d, 4, 64);
            d += __shfl_xor(d, 8, 64);
            if (sub == 0) yp_s[row] = gelu_exact(d);
        }
    }
    __syncthreads();

    // Stage 3: this block's 112-row slice of ab.
    {
        const int sub = tid & 7;
        const int rg  = tid >> 3;         // 0..127, use <112
        if (rg < 112) {
            const int row = slice * 112 + rg;
            const float* W = (row < 448) ? (wA + (size_t)row * CC)
                                         : (wB + (size_t)(row - 448) * CC);
            const float4* wr  = reinterpret_cast<const float4*>(W);
            const float4* ps4 = reinterpret_cast<const float4*>(yp_s);
            float d = 0.0f;
            #pragma unroll
            for (int k = 0; k < 8; ++k) d += dot4(wr[sub + 8 * k], ps4[sub + 8 * k]);
            d += __shfl_xor(d, 1, 64);
            d += __shfl_xor(d, 2, 64);
            d += __shfl_xor(d, 4, 64);
            if (sub == 0) ab[(size_t)b * 896 + row] = d;
        }
    }
}

// ---------------------------------------------------------------------------
// Kernel 3: stage 4 + broadcast fused.  256 blocks = 8 slices per batch.
// Sigmoid map computed once per block into LDS, then streamed out with
// NON-TEMPORAL stores (out is never re-read; avoid evicting x from L3).
// ---------------------------------------------------------------------------
__global__ __launch_bounds__(1024) void bcast_map_kernel(
        const float* __restrict__ ab, vf4* __restrict__ out) {
    const int b     = blockIdx.x >> 3;    // batch
    const int slice = blockIdx.x & 7;     // channel slice (32 channels)
    const int tid   = threadIdx.x;

    __shared__ float ab_s[896];
    __shared__ float attn_s[HWN];         // 12.5 KB

    if (tid < 896) ab_s[tid] = ab[(size_t)b * 896 + tid];
    __syncthreads();

    for (int p = tid; p < HWN; p += 1024) {
        const int i = p / WW;
        const int j = p - i * WW;
        float m = 0.0f;
        #pragma unroll
        for (int r = 0; r < RNK; ++r)
            m += ab_s[i * RNK + r] * ab_s[448 + r * WW + j];
        attn_s[p] = 1.0f / (1.0f + expf(-m));
    }
    __syncthreads();

    const vf4* a4 = reinterpret_cast<const vf4*>(attn_s);
    vf4* base = out + ((size_t)(b * CC + slice * 32)) * HW4;
    for (int idx = tid; idx < 32 * HW4; idx += 1024) {
        const int p = idx % HW4;
        __builtin_nontemporal_store(a4[p], base + idx);
    }
}

// ---------------------------------------------------------------------------
extern "C" void kernel_launch(void* const* d_in, const int* in_sizes, int n_in,
                              void* d_out, int out_size, void* d_ws, size_t ws_size,
                              hipStream_t stream) {
    const float* x  = (const float*)d_in[0];
    const float* w1 = (const float*)d_in[1];
    const float* w2 = (const float*)d_in[2];
    const float* wA = (const float*)d_in[3];
    const float* wB = (const float*)d_in[4];

    // ws layout (floats): y[B*C] | ab[B*896]
    float* y  = (float*)d_ws;
    float* ab = y + BB * CC;

    pool_kernel<<<BB * CC, 256, 0, stream>>>(x, y);
    middle_kernel<<<BB * 8, 1024, 0, stream>>>(y, w1, w2, wA, wB, ab);
    bcast_map_kernel<<<BB * 8, 1024, 0, stream>>>(ab, reinterpret_cast<vf4*>(d_out));
}